// Round 2
// baseline (400.283 us; speedup 1.0000x reference)
//
#include <hip/hip_runtime.h>
#include <math.h>

#define E_PER_B 73536
#define E_TOT   588288
#define NB 8
#define NN 384
#define NF 128

// ---- threefry2x32, JAX partitionable scheme (default since jax 0.4.36) ----
// element l: ctr = (hi=0, lo=l), key = (0, 42), bits = out0 ^ out1
__device__ __forceinline__ float gumbel_noise(unsigned l) {
  unsigned x0 = 0u;
  unsigned x1 = l;
  const unsigned ks0 = 0u, ks1 = 42u, ks2 = 0x1BD11BDAu ^ 42u;
  x0 += ks0; x1 += ks1;
#define TF_R(r) { x0 += x1; x1 = (x1 << (r)) | (x1 >> (32 - (r))); x1 ^= x0; }
  TF_R(13) TF_R(15) TF_R(26) TF_R(6)
  x0 += ks1; x1 += ks2 + 1u;
  TF_R(17) TF_R(29) TF_R(16) TF_R(24)
  x0 += ks2; x1 += ks0 + 2u;
  TF_R(13) TF_R(15) TF_R(26) TF_R(6)
  x0 += ks0; x1 += ks1 + 3u;
  TF_R(17) TF_R(29) TF_R(16) TF_R(24)
  x0 += ks1; x1 += ks2 + 4u;
  TF_R(13) TF_R(15) TF_R(26) TF_R(6)
  x0 += ks2; x1 += ks0 + 5u;
#undef TF_R
  unsigned bits = x0 ^ x1;
  float u = __uint_as_float((bits >> 9) | 0x3f800000u) - 1.0f; // [0,1)
  u = fmaxf(u, 1.17549435e-38f);                               // minval=tiny
  float t = (float)(-log((double)u));   // mimic ref's fp32 intermediate
  return (float)(-log((double)t));
}

// ---------------- k0: fold LN2 affine into W3 ----------------
__global__ __launch_bounds__(128) void k0_fold(
    const float* __restrict__ g2, const float* __restrict__ bt2,
    const float* __restrict__ W3, const float* __restrict__ b3,
    float* __restrict__ w3g, float* __restrict__ d2c3) {
  __shared__ double red[256];
  int f = threadIdx.x;
  float wg = g2[f] * W3[f];
  w3g[f] = wg;
  red[f]       = (double)g2[f]  * (double)W3[f];
  red[128 + f] = (double)bt2[f] * (double)W3[f];
  __syncthreads();
  if (f == 0) {
    double d2 = 0.0, c3 = 0.0;
    for (int i = 0; i < 128; ++i) { d2 += red[i]; c3 += red[128 + i]; }
    d2c3[0] = (float)d2;
    d2c3[1] = (float)(c3 + (double)b3[0]);
  }
}

// ---------------- k1: P = nodes@W1[:128], Q = nodes@W1[128:] ----------------
__global__ __launch_bounds__(128) void k1_pq(
    const float* __restrict__ nodes, const float* __restrict__ W1,
    float* __restrict__ P, float* __restrict__ Q) {
  __shared__ float x[128];
  int row = blockIdx.x;          // 0..3071 == b*384+n
  int f = threadIdx.x;
  x[f] = nodes[row * 128 + f];
  __syncthreads();
  float p = 0.f, q = 0.f;
#pragma unroll 4
  for (int k = 0; k < 128; ++k) {
    float xk = x[k];
    p += xk * W1[k * 128 + f];
    q += xk * W1[(128 + k) * 128 + f];
  }
  P[row * 128 + f] = p;
  Q[row * 128 + f] = q;
}

// ---------------- k2: fused edge MLP -> logits[b][si][so] ----------------
__global__ __launch_bounds__(256) void k2_edges(
    const float* __restrict__ P, const float* __restrict__ Q,
    const float* __restrict__ b1, const float* __restrict__ g1,
    const float* __restrict__ bt1, const float* __restrict__ W2,
    const float* __restrict__ b2, const float* __restrict__ w3g,
    const float* __restrict__ d2c3, float* __restrict__ logits) {
  __shared__ float sh1[128 * 132];   // also reused as reduction buffer
  __shared__ float sw2[128 * 128];
  __shared__ float scst[5 * 128];    // b1,g1,bt1,b2,w3g
  __shared__ unsigned smeta[128];
  __shared__ float sd2c3[2];

  const int tid = threadIdx.x;
  if (tid < 128) {
    scst[tid]       = b1[tid];
    scst[128 + tid] = g1[tid];
    scst[256 + tid] = bt1[tid];
    scst[384 + tid] = b2[tid];
    scst[512 + tid] = w3g[tid];
  }
  if (tid == 128) { sd2c3[0] = d2c3[0]; sd2c3[1] = d2c3[1]; }
  __syncthreads();

  if (tid < 128) {
    // ---- phase A: one thread = one edge; LN1 fully in registers ----
    int g = blockIdx.x * 128 + tid;          // grid sized exactly: g < E_TOT
    int b = g / E_PER_B;
    int t = g - b * E_PER_B;
    int si = (int)((1.0 + sqrt(1.0 + 8.0 * (double)t)) * 0.5);
    while (si * (si - 1) / 2 > t) --si;
    while ((si + 1) * si / 2 <= t) ++si;
    int so = t - si * (si - 1) / 2;
    smeta[tid] = (unsigned)((b * NN + si) * (NN - 1) + so);

    const float4* P4 = (const float4*)(P + (size_t)(b * NN + si) * 128);
    const float4* Q4 = (const float4*)(Q + (size_t)(b * NN + so) * 128);
    const float4* B14 = (const float4*)(scst);
    float4 a[32];
    float sum = 0.f;
#pragma unroll
    for (int k4 = 0; k4 < 32; ++k4) {
      float4 p = P4[k4], q = Q4[k4], bb = B14[k4];
      float4 v;
      v.x = fmaxf(p.x + q.x + bb.x, 0.f);
      v.y = fmaxf(p.y + q.y + bb.y, 0.f);
      v.z = fmaxf(p.z + q.z + bb.z, 0.f);
      v.w = fmaxf(p.w + q.w + bb.w, 0.f);
      a[k4] = v;
      sum += v.x; sum += v.y; sum += v.z; sum += v.w;
    }
    float m = sum * 0.0078125f;
    float ss = 0.f;
#pragma unroll
    for (int k4 = 0; k4 < 32; ++k4) {
      float dx;
      dx = a[k4].x - m; ss += dx * dx;
      dx = a[k4].y - m; ss += dx * dx;
      dx = a[k4].z - m; ss += dx * dx;
      dx = a[k4].w - m; ss += dx * dx;
    }
    float var = ss * 0.0078125f;
    float rs = 1.0f / sqrtf(var + 1e-5f);
    const float* G1 = scst + 128;
    const float* BT1 = scst + 256;
#pragma unroll
    for (int k4 = 0; k4 < 32; ++k4) {
      float4 h;
      h.x = (a[k4].x - m) * rs * G1[4 * k4 + 0] + BT1[4 * k4 + 0];
      h.y = (a[k4].y - m) * rs * G1[4 * k4 + 1] + BT1[4 * k4 + 1];
      h.z = (a[k4].z - m) * rs * G1[4 * k4 + 2] + BT1[4 * k4 + 2];
      h.w = (a[k4].w - m) * rs * G1[4 * k4 + 3] + BT1[4 * k4 + 3];
      *(float4*)&sh1[tid * 132 + 4 * k4] = h;
    }
  } else {
    // ---- threads 128..255: stage W2 into LDS (coalesced float4) ----
    const float4* W24 = (const float4*)W2;
    float4* SW24 = (float4*)sw2;
    for (int i = tid - 128; i < 4096; i += 128) SW24[i] = W24[i];
  }
  __syncthreads();

  // ---- phase C: GEMM h1[128x128] @ W2[128x128], 8e x 8f per thread ----
  const int eg = tid & 15;      // edge group: edges eg + 16*r
  const int fg = tid >> 4;      // feature group: 8*fg .. 8*fg+7
  float acc[8][8];
#pragma unroll
  for (int r = 0; r < 8; ++r)
#pragma unroll
    for (int c = 0; c < 8; ++c) acc[r][c] = 0.f;

  const float* h1base = sh1 + eg * 132;
  const float* w2base = sw2 + fg * 8;
  for (int kb = 0; kb < 32; ++kb) {
    float4 av[8];
#pragma unroll
    for (int r = 0; r < 8; ++r)
      av[r] = *(const float4*)(h1base + r * (16 * 132) + kb * 4);
#pragma unroll
    for (int kk = 0; kk < 4; ++kk) {
      float4 w0 = *(const float4*)(w2base + (kb * 4 + kk) * 128);
      float4 w1 = *(const float4*)(w2base + (kb * 4 + kk) * 128 + 4);
#pragma unroll
      for (int r = 0; r < 8; ++r) {
        float s = (kk == 0) ? av[r].x : (kk == 1) ? av[r].y : (kk == 2) ? av[r].z : av[r].w;
        acc[r][0] += s * w0.x; acc[r][1] += s * w0.y;
        acc[r][2] += s * w0.z; acc[r][3] += s * w0.w;
        acc[r][4] += s * w1.x; acc[r][5] += s * w1.y;
        acc[r][6] += s * w1.z; acc[r][7] += s * w1.w;
      }
    }
  }

  __syncthreads();              // everyone done reading sh1; reuse as sred
  float* sred = sh1;            // [16 fg][128 e][3]
  const float* B2 = scst + 384;
  const float* W3S = scst + 512;
#pragma unroll
  for (int r = 0; r < 8; ++r) {
    float s = 0.f, ss2 = 0.f, d = 0.f;
#pragma unroll
    for (int c = 0; c < 8; ++c) {
      float pre = acc[r][c] + B2[fg * 8 + c];
      float rr = fmaxf(pre, 0.f);
      s += rr; ss2 += rr * rr; d += rr * W3S[fg * 8 + c];
    }
    int e = eg + 16 * r;
    sred[(fg * 128 + e) * 3 + 0] = s;
    sred[(fg * 128 + e) * 3 + 1] = ss2;
    sred[(fg * 128 + e) * 3 + 2] = d;
  }
  __syncthreads();
  if (tid < 128) {
    float s = 0.f, ss2 = 0.f, d = 0.f;
    for (int f = 0; f < 16; ++f) {
      s   += sred[(f * 128 + tid) * 3 + 0];
      ss2 += sred[(f * 128 + tid) * 3 + 1];
      d   += sred[(f * 128 + tid) * 3 + 2];
    }
    float m2 = s * 0.0078125f;
    float var = fmaxf(ss2 * 0.0078125f - m2 * m2, 0.f);
    float rs2 = 1.0f / sqrtf(var + 1e-5f);
    float logit = rs2 * d - m2 * rs2 * sd2c3[0] + sd2c3[1];
    logits[smeta[tid]] = logit;
  }
}

// ---------------- kz: zero output ----------------
__global__ __launch_bounds__(256) void kz_zero(float4* __restrict__ out, int n4) {
  int i = blockIdx.x * 256 + threadIdx.x;
  if (i < n4) out[i] = make_float4(0.f, 0.f, 0.f, 0.f);
}

// ---------------- k3: per (b,i,sample) gumbel argmax -> out=1 ----------------
__global__ __launch_bounds__(320) void k3_argmax(
    const float* __restrict__ logits, float* __restrict__ out) {
  int blk = blockIdx.x;
  int b = blk / NN;
  int i = blk - b * NN;
  if (i == 0) return;                    // row 0's pick lands on the diagonal
  int s = threadIdx.x >> 6;              // sample 0..4 (one wave each)
  int lane = threadIdx.x & 63;
  const float* row = logits + (size_t)(b * NN + i) * (NN - 1);
  float best = -INFINITY;
  int bestj = 0x7fffffff;
  unsigned lbase = ((unsigned)((s * NB + b) * NN + i)) * (NN - 1);
  for (int j = lane; j < i; j += 64) {
    float v = row[j] + gumbel_noise(lbase + (unsigned)j);
    if (v > best) { best = v; bestj = j; }   // strict > keeps first index
  }
  for (int off = 32; off; off >>= 1) {
    float ov = __shfl_down(best, off);
    int oj = __shfl_down(bestj, off);
    if (ov > best || (ov == best && oj < bestj)) { best = ov; bestj = oj; }
  }
  if (lane == 0) out[((size_t)(b * NN) + i) * NN + bestj] = 1.0f;
}

// ---------------- launch ----------------
extern "C" void kernel_launch(void* const* d_in, const int* in_sizes, int n_in,
                              void* d_out, int out_size, void* d_ws, size_t ws_size,
                              hipStream_t stream) {
  const float* nodes = (const float*)d_in[0];
  const float* W1  = (const float*)d_in[1];
  const float* b1  = (const float*)d_in[2];
  const float* g1  = (const float*)d_in[3];
  const float* bt1 = (const float*)d_in[4];
  const float* W2  = (const float*)d_in[5];
  const float* b2  = (const float*)d_in[6];
  const float* g2  = (const float*)d_in[7];
  const float* bt2 = (const float*)d_in[8];
  const float* W3  = (const float*)d_in[9];
  const float* b3  = (const float*)d_in[10];

  float* ws     = (float*)d_ws;
  float* P      = ws;                 // 393216 floats
  float* Q      = ws + 393216;        // 393216
  float* w3g    = ws + 786432;        // 128
  float* d2c3   = ws + 786560;        // 2
  float* logits = ws + 786688;        // 8*384*383 = 1176576

  hipLaunchKernelGGL(k0_fold, dim3(1), dim3(128), 0, stream, g2, bt2, W3, b3, w3g, d2c3);
  hipLaunchKernelGGL(k1_pq, dim3(NB * NN), dim3(128), 0, stream, nodes, W1, P, Q);
  hipLaunchKernelGGL(k2_edges, dim3(E_TOT / 128), dim3(256), 0, stream,
                     P, Q, b1, g1, bt1, W2, b2, w3g, d2c3, logits);
  int n4 = out_size / 4;              // 294912
  hipLaunchKernelGGL(kz_zero, dim3((n4 + 255) / 256), dim3(256), 0, stream,
                     (float4*)d_out, n4);
  hipLaunchKernelGGL(k3_argmax, dim3(NB * NN), dim3(320), 0, stream, logits, (float*)d_out);
}

// Round 3
// 329.930 us; speedup vs baseline: 1.2132x; 1.2132x over previous
//
#include <hip/hip_runtime.h>
#include <math.h>

#define E_PER_B 73536
#define E_TOT   588288
#define NB 8
#define NN 384
#define NF 128

// ---- threefry2x32, JAX partitionable scheme (default since jax 0.4.36) ----
// element l: ctr = (hi=0, lo=l), key = (0, 42), bits = out0 ^ out1
__device__ __forceinline__ float gumbel_noise(unsigned l) {
  unsigned x0 = 0u;
  unsigned x1 = l;
  const unsigned ks0 = 0u, ks1 = 42u, ks2 = 0x1BD11BDAu ^ 42u;
  x0 += ks0; x1 += ks1;
#define TF_R(r) { x0 += x1; x1 = (x1 << (r)) | (x1 >> (32 - (r))); x1 ^= x0; }
  TF_R(13) TF_R(15) TF_R(26) TF_R(6)
  x0 += ks1; x1 += ks2 + 1u;
  TF_R(17) TF_R(29) TF_R(16) TF_R(24)
  x0 += ks2; x1 += ks0 + 2u;
  TF_R(13) TF_R(15) TF_R(26) TF_R(6)
  x0 += ks0; x1 += ks1 + 3u;
  TF_R(17) TF_R(29) TF_R(16) TF_R(24)
  x0 += ks1; x1 += ks2 + 4u;
  TF_R(13) TF_R(15) TF_R(26) TF_R(6)
  x0 += ks2; x1 += ks0 + 5u;
#undef TF_R
  unsigned bits = x0 ^ x1;
  float u = __uint_as_float((bits >> 9) | 0x3f800000u) - 1.0f; // [0,1)
  u = fmaxf(u, 1.17549435e-38f);                               // minval=tiny
  float t = (float)(-log((double)u));   // mimic ref's fp32 intermediate
  return (float)(-log((double)t));
}

// ---------------- k0: fold LN2 affine into W3 ----------------
__global__ __launch_bounds__(128) void k0_fold(
    const float* __restrict__ g2, const float* __restrict__ bt2,
    const float* __restrict__ W3, const float* __restrict__ b3,
    float* __restrict__ w3g, float* __restrict__ d2c3) {
  __shared__ double red[256];
  int f = threadIdx.x;
  float wg = g2[f] * W3[f];
  w3g[f] = wg;
  red[f]       = (double)g2[f]  * (double)W3[f];
  red[128 + f] = (double)bt2[f] * (double)W3[f];
  __syncthreads();
  if (f == 0) {
    double d2 = 0.0, c3 = 0.0;
    for (int i = 0; i < 128; ++i) { d2 += red[i]; c3 += red[128 + i]; }
    d2c3[0] = (float)d2;
    d2c3[1] = (float)(c3 + (double)b3[0]);
  }
}

// ---------------- k1: P = nodes@W1[:128], Q = nodes@W1[128:] ----------------
__global__ __launch_bounds__(128) void k1_pq(
    const float* __restrict__ nodes, const float* __restrict__ W1,
    float* __restrict__ P, float* __restrict__ Q) {
  __shared__ float x[128];
  int row = blockIdx.x;          // 0..3071 == b*384+n
  int f = threadIdx.x;
  x[f] = nodes[row * 128 + f];
  __syncthreads();
  float p = 0.f, q = 0.f;
#pragma unroll 4
  for (int k = 0; k < 128; ++k) {
    float xk = x[k];
    p += xk * W1[k * 128 + f];
    q += xk * W1[(128 + k) * 128 + f];
  }
  P[row * 128 + f] = p;
  Q[row * 128 + f] = q;
}

// ---------------- k2: fused edge MLP -> logits[b][si][so] ----------------
// 128 edges/block, 256 threads. LDS = h1 tile only (~72 KB) -> 2 blocks/CU.
// W2 is read straight from global (L1/L2-resident, 16-lane broadcast).
__global__ __launch_bounds__(256) void k2_edges(
    const float* __restrict__ P, const float* __restrict__ Q,
    const float* __restrict__ b1, const float* __restrict__ g1,
    const float* __restrict__ bt1, const float* __restrict__ W2,
    const float* __restrict__ b2, const float* __restrict__ w3g,
    const float* __restrict__ d2c3, float* __restrict__ logits) {
  __shared__ float sh1[128 * 132];   // h1 tile; reused as epilogue reduction buf
  __shared__ float scst[5 * 128];    // b1,g1,bt1,b2,w3g
  __shared__ float sredA[256];
  __shared__ float sredB[256];
  __shared__ unsigned smeta[128];
  __shared__ float sd2c3[2];

  const int tid = threadIdx.x;
  if (tid < 128) {
    scst[tid]       = b1[tid];
    scst[128 + tid] = g1[tid];
    scst[256 + tid] = bt1[tid];
    scst[384 + tid] = b2[tid];
    scst[512 + tid] = w3g[tid];
  }
  if (tid == 128) { sd2c3[0] = d2c3[0]; sd2c3[1] = d2c3[1]; }
  __syncthreads();

  // ---- phase A: 2 threads per edge (feature halves); LN1 via LDS partials --
  {
    const int e = tid & 127;
    const int half = tid >> 7;               // 0: k 0..63, 1: k 64..127
    int g = blockIdx.x * 128 + e;            // grid sized exactly: g < E_TOT
    int b = g / E_PER_B;
    int t = g - b * E_PER_B;
    int si = (int)((1.0 + sqrt(1.0 + 8.0 * (double)t)) * 0.5);
    while (si * (si - 1) / 2 > t) --si;
    while ((si + 1) * si / 2 <= t) ++si;
    int so = t - si * (si - 1) / 2;
    if (half == 0) smeta[e] = (unsigned)((b * NN + si) * (NN - 1) + so);

    const float4* P4 = (const float4*)(P + (size_t)(b * NN + si) * 128) + half * 16;
    const float4* Q4 = (const float4*)(Q + (size_t)(b * NN + so) * 128) + half * 16;
    const float4* B14 = (const float4*)(scst) + half * 16;
    float4 a[16];
    float sum = 0.f;
#pragma unroll
    for (int k4 = 0; k4 < 16; ++k4) {
      float4 p = P4[k4], q = Q4[k4], bb = B14[k4];
      float4 v;
      v.x = fmaxf(p.x + q.x + bb.x, 0.f);
      v.y = fmaxf(p.y + q.y + bb.y, 0.f);
      v.z = fmaxf(p.z + q.z + bb.z, 0.f);
      v.w = fmaxf(p.w + q.w + bb.w, 0.f);
      a[k4] = v;
      sum += v.x; sum += v.y; sum += v.z; sum += v.w;
    }
    sredA[half * 128 + e] = sum;
    __syncthreads();
    float m = (sredA[e] + sredA[128 + e]) * 0.0078125f;
    float ss = 0.f;
#pragma unroll
    for (int k4 = 0; k4 < 16; ++k4) {
      float dx;
      dx = a[k4].x - m; ss += dx * dx;
      dx = a[k4].y - m; ss += dx * dx;
      dx = a[k4].z - m; ss += dx * dx;
      dx = a[k4].w - m; ss += dx * dx;
    }
    sredB[half * 128 + e] = ss;
    __syncthreads();
    float var = (sredB[e] + sredB[128 + e]) * 0.0078125f;
    float rs = 1.0f / sqrtf(var + 1e-5f);
    const float* G1 = scst + 128 + half * 64;
    const float* BT1 = scst + 256 + half * 64;
#pragma unroll
    for (int k4 = 0; k4 < 16; ++k4) {
      float4 h;
      h.x = (a[k4].x - m) * rs * G1[4 * k4 + 0] + BT1[4 * k4 + 0];
      h.y = (a[k4].y - m) * rs * G1[4 * k4 + 1] + BT1[4 * k4 + 1];
      h.z = (a[k4].z - m) * rs * G1[4 * k4 + 2] + BT1[4 * k4 + 2];
      h.w = (a[k4].w - m) * rs * G1[4 * k4 + 3] + BT1[4 * k4 + 3];
      *(float4*)&sh1[e * 132 + half * 64 + 4 * k4] = h;
    }
  }
  __syncthreads();

  // ---- phase C: GEMM h1[128x128] @ W2[128x128], 8e x 8f per thread ----
  // W2 rows read from global: 16 lanes broadcast per fg slice, L1/L2 hit.
  const int eg = tid & 15;      // edge group: edges eg + 16*r
  const int fg = tid >> 4;      // feature group: 8*fg .. 8*fg+7
  float acc[8][8];
#pragma unroll
  for (int r = 0; r < 8; ++r)
#pragma unroll
    for (int c = 0; c < 8; ++c) acc[r][c] = 0.f;

  const float* h1base = sh1 + eg * 132;
  const float* wp = W2 + fg * 8;
  for (int kb = 0; kb < 32; ++kb) {
    float4 av[8];
#pragma unroll
    for (int r = 0; r < 8; ++r)
      av[r] = *(const float4*)(h1base + r * (16 * 132) + kb * 4);
#pragma unroll
    for (int kk = 0; kk < 4; ++kk) {
      float4 w0 = *(const float4*)(wp);
      float4 w1 = *(const float4*)(wp + 4);
      wp += 128;
#pragma unroll
      for (int r = 0; r < 8; ++r) {
        float s = (kk == 0) ? av[r].x : (kk == 1) ? av[r].y : (kk == 2) ? av[r].z : av[r].w;
        acc[r][0] += s * w0.x; acc[r][1] += s * w0.y;
        acc[r][2] += s * w0.z; acc[r][3] += s * w0.w;
        acc[r][4] += s * w1.x; acc[r][5] += s * w1.y;
        acc[r][6] += s * w1.z; acc[r][7] += s * w1.w;
      }
    }
  }

  __syncthreads();              // everyone done reading sh1; reuse as sred
  float* sred = sh1;            // [16 fg][128 e][3]
  const float* B2 = scst + 384;
  const float* W3S = scst + 512;
#pragma unroll
  for (int r = 0; r < 8; ++r) {
    float s = 0.f, ss2 = 0.f, d = 0.f;
#pragma unroll
    for (int c = 0; c < 8; ++c) {
      float pre = acc[r][c] + B2[fg * 8 + c];
      float rr = fmaxf(pre, 0.f);
      s += rr; ss2 += rr * rr; d += rr * W3S[fg * 8 + c];
    }
    int e = eg + 16 * r;
    sred[(fg * 128 + e) * 3 + 0] = s;
    sred[(fg * 128 + e) * 3 + 1] = ss2;
    sred[(fg * 128 + e) * 3 + 2] = d;
  }
  __syncthreads();
  if (tid < 128) {
    float s = 0.f, ss2 = 0.f, d = 0.f;
    for (int f = 0; f < 16; ++f) {
      s   += sred[(f * 128 + tid) * 3 + 0];
      ss2 += sred[(f * 128 + tid) * 3 + 1];
      d   += sred[(f * 128 + tid) * 3 + 2];
    }
    float m2 = s * 0.0078125f;
    float var = fmaxf(ss2 * 0.0078125f - m2 * m2, 0.f);
    float rs2 = 1.0f / sqrtf(var + 1e-5f);
    float logit = rs2 * d - m2 * rs2 * sd2c3[0] + sd2c3[1];
    logits[smeta[tid]] = logit;
  }
}

// ---------------- kz: zero output ----------------
__global__ __launch_bounds__(256) void kz_zero(float4* __restrict__ out, int n4) {
  int i = blockIdx.x * 256 + threadIdx.x;
  if (i < n4) out[i] = make_float4(0.f, 0.f, 0.f, 0.f);
}

// ---------------- k3: per (b,i,sample) gumbel argmax -> out=1 ----------------
__global__ __launch_bounds__(320) void k3_argmax(
    const float* __restrict__ logits, float* __restrict__ out) {
  int blk = blockIdx.x;
  int b = blk / NN;
  int i = blk - b * NN;
  if (i == 0) return;                    // row 0's pick lands on the diagonal
  int s = threadIdx.x >> 6;              // sample 0..4 (one wave each)
  int lane = threadIdx.x & 63;
  const float* row = logits + (size_t)(b * NN + i) * (NN - 1);
  float best = -INFINITY;
  int bestj = 0x7fffffff;
  unsigned lbase = ((unsigned)((s * NB + b) * NN + i)) * (NN - 1);
  for (int j = lane; j < i; j += 64) {
    float v = row[j] + gumbel_noise(lbase + (unsigned)j);
    if (v > best) { best = v; bestj = j; }   // strict > keeps first index
  }
  for (int off = 32; off; off >>= 1) {
    float ov = __shfl_down(best, off);
    int oj = __shfl_down(bestj, off);
    if (ov > best || (ov == best && oj < bestj)) { best = ov; bestj = oj; }
  }
  if (lane == 0) out[((size_t)(b * NN) + i) * NN + bestj] = 1.0f;
}

// ---------------- launch ----------------
extern "C" void kernel_launch(void* const* d_in, const int* in_sizes, int n_in,
                              void* d_out, int out_size, void* d_ws, size_t ws_size,
                              hipStream_t stream) {
  const float* nodes = (const float*)d_in[0];
  const float* W1  = (const float*)d_in[1];
  const float* b1  = (const float*)d_in[2];
  const float* g1  = (const float*)d_in[3];
  const float* bt1 = (const float*)d_in[4];
  const float* W2  = (const float*)d_in[5];
  const float* b2  = (const float*)d_in[6];
  const float* g2  = (const float*)d_in[7];
  const float* bt2 = (const float*)d_in[8];
  const float* W3  = (const float*)d_in[9];
  const float* b3  = (const float*)d_in[10];

  float* ws     = (float*)d_ws;
  float* Pw     = ws;                 // 393216 floats
  float* Qw     = ws + 393216;        // 393216
  float* w3g    = ws + 786432;        // 128
  float* d2c3   = ws + 786560;        // 2
  float* logits = ws + 786688;        // 8*384*383 = 1176576

  hipLaunchKernelGGL(k0_fold, dim3(1), dim3(128), 0, stream, g2, bt2, W3, b3, w3g, d2c3);
  hipLaunchKernelGGL(k1_pq, dim3(NB * NN), dim3(128), 0, stream, nodes, W1, Pw, Qw);
  hipLaunchKernelGGL(k2_edges, dim3(E_TOT / 128), dim3(256), 0, stream,
                     Pw, Qw, b1, g1, bt1, W2, b2, w3g, d2c3, logits);
  int n4 = out_size / 4;              // 294912
  hipLaunchKernelGGL(kz_zero, dim3((n4 + 255) / 256), dim3(256), 0, stream,
                     (float4*)d_out, n4);
  hipLaunchKernelGGL(k3_argmax, dim3(NB * NN), dim3(320), 0, stream, logits, (float*)d_out);
}